// Round 1
// baseline (224.844 us; speedup 1.0000x reference)
//
#include <hip/hip_runtime.h>

// ---------------------------------------------------------------------------
// SimpleVisionAttention on MI355X (gfx950)
// S=2048, DIM=1280 (16 heads x 80), fp32 in/out, f16 MFMA internally.
//
// Pipeline:
//   K1  fused cast fp32 -> f16   (hs, w_qkv, w_proj)
//   K2  QKV GEMM  64x128 tiles, BK=64 dual-panel (half the barriers of BK=32)
//   K3  fused RoPE + repack Qh/Kh [h][s][96] + V transpose -> Vt[h][d][s]
//   K4  flash attention, transposed dataflow (S^T->P^T in regs), fixed-max
//       base-2 softmax, KV-split x4. v2: T14 issue-early staging (hoisted
//       per-thread chunk addressing), PV via 16x16x32 MFMA with
//       cvt_pkrtz + permlane32/16_swap P-repack, plain d-major V tile.
//   K4b combine 4 partials (weighted by per-split l)
//   K5  proj GEMM 64x128 tiles, BK=64 dual-panel
// ---------------------------------------------------------------------------

#define SEQLEN   2048
#define DIMM     1280
#define NHEADS   16
#define HD       80
#define HDP      96          // padded head dim for Q/K (3 x 32 mfma K-steps)
#define QKV_N    3840
#define NSPLIT   4
#define KVSPAN   (SEQLEN / NSPLIT)
// SCALE * log2(e) folded into Q at rope time; softmax done in base-2.
#define QSCALE_LOG2E 0.16130083587064776f   // 80^-0.5 * 1.4426950408889634

#define KSTRIDE  104  // K-tile row stride (52 dw): 2-way start banks = free
#define VSTRIDE  72   // V-tile row stride (36 dw): 2-way start banks = free
#define VSOFF    (64 * KSTRIDE)   // V tile base inside Sb (halves)

// device base-2 exp: v_exp_f32 (NOT __exp2f — collides with glibc math.h)
#define EXP2F(x) __builtin_amdgcn_exp2f(x)

// async global->LDS, 16B per lane; LDS dest must be waveBase + lane*16
#define GLD16(gptr, lptr)                                                      \
    __builtin_amdgcn_global_load_lds(                                          \
        (const __attribute__((address_space(1))) void*)(gptr),                 \
        (__attribute__((address_space(3))) void*)(lptr), 16, 0, 0)

typedef float f32x4 __attribute__((ext_vector_type(4)));
typedef _Float16 half8 __attribute__((ext_vector_type(8)));
typedef _Float16 half4 __attribute__((ext_vector_type(4)));
typedef int int4v __attribute__((ext_vector_type(4)));

static __device__ __forceinline__ f32x4 mfma_16x16x32(half8 a, half8 b, f32x4 c) {
    return __builtin_amdgcn_mfma_f32_16x16x32_f16(a, b, c, 0, 0, 0);
}

// ---------------------------------------------------------------------------
// One fused cast kernel for the three fp32->f16 conversions.
__global__ __launch_bounds__(256)
void cast_all(const float* __restrict__ hs, const float* __restrict__ wq,
              const float* __restrict__ wp, _Float16* __restrict__ dhs,
              _Float16* __restrict__ dwq, _Float16* __restrict__ dwp) {
    const int n1 = SEQLEN * DIMM / 4, n2 = QKV_N * DIMM / 4, n3 = DIMM * DIMM / 4;
    int i = blockIdx.x * 256 + threadIdx.x;
    const float4* src; half4* dst; int j;
    if (i < n1)           { src = (const float4*)hs; dst = (half4*)dhs; j = i; }
    else if (i < n1 + n2) { src = (const float4*)wq; dst = (half4*)dwq; j = i - n1; }
    else if (i < n1 + n2 + n3) { src = (const float4*)wp; dst = (half4*)dwp; j = i - n1 - n2; }
    else return;
    const float4 v = src[j];
    half4 h;
    h.x = (_Float16)v.x; h.y = (_Float16)v.y;
    h.z = (_Float16)v.z; h.w = (_Float16)v.w;
    dst[j] = h;
}

// ---------------------------------------------------------------------------
// C[m][n] = sum_k A[m][k] * B[n][k] + bias[n]
// A: M x K f16 row-major, B: N x K f16 row-major (i.e. B^T layout).
// 64x128 block tile, 4 waves 2x2 (each 32x64, 2x4 mfma tiles).
// BK=64 as TWO BK=32 PANELS: keeps the LDS row stride at 32 halves (a flat
// 64-stride would put lane-strided ds_reads on one bank = 16-way conflict,
// and global_load_lds forbids padding). Halves barrier count vs BK=32:
// 20 K-iters x 2 barriers, 16 MFMA + 6 GLD16 + 12 ds_read_b128 per iter.
template<bool OUT_F16>
__global__ __launch_bounds__(256, 2)
void gemm_bt64(const _Float16* __restrict__ A, const _Float16* __restrict__ B,
               const float* __restrict__ bias, void* __restrict__ Cout,
               int M, int N, int K) {
    __shared__ __align__(16) _Float16 As[2][64 * 32];    // 8 KB
    __shared__ __align__(16) _Float16 Bs[2][128 * 32];   // 16 KB
    const int tid  = threadIdx.x;
    const int lane = tid & 63;
    const int wave = tid >> 6;
    const int l15  = lane & 15;
    const int quad = lane >> 4;
    const int wm   = wave & 1;
    const int wn   = wave >> 1;
    const long bm = blockIdx.x, bn = blockIdx.y;

    const _Float16* Ag = A + bm * 64 * (long)K;
    const _Float16* Bg = B + bn * 128 * (long)K;

    const int srow = lane >> 2;            // 0..15 within chunk
    const int scol = (lane & 3) * 8;       // halves
    f32x4 acc[2][4] = {};

    for (int k0 = 0; k0 < K; k0 += 64) {
        __syncthreads();
#pragma unroll
        for (int p = 0; p < 2; p++) {
            const int kp = k0 + p * 32;
            const long arow = 16 * wave + srow;
            GLD16(Ag + arow * K + kp + scol, &As[p][512 * wave + lane * 8]);
#pragma unroll
            for (int cc = 0; cc < 2; cc++) {
                const int c = wave + cc * 4;
                const long brow = 16 * c + srow;
                GLD16(Bg + brow * K + kp + scol, &Bs[p][512 * c + lane * 8]);
            }
        }
        __syncthreads();
#pragma unroll
        for (int p = 0; p < 2; p++) {
            half8 af[2], bf[4];
#pragma unroll
            for (int t = 0; t < 2; t++)
                af[t] = *(const half8*)&As[p][(wm * 32 + t * 16 + l15) * 32 + quad * 8];
#pragma unroll
            for (int t = 0; t < 4; t++)
                bf[t] = *(const half8*)&Bs[p][(wn * 64 + t * 16 + l15) * 32 + quad * 8];
#pragma unroll
            for (int mt = 0; mt < 2; mt++)
#pragma unroll
                for (int nt = 0; nt < 4; nt++)
                    acc[mt][nt] = mfma_16x16x32(af[mt], bf[nt], acc[mt][nt]);
        }
    }

    float bv[4];
#pragma unroll
    for (int nt = 0; nt < 4; nt++)
        bv[nt] = bias[bn * 128 + wn * 64 + nt * 16 + l15];

#pragma unroll
    for (int mt = 0; mt < 2; mt++) {
#pragma unroll
        for (int r = 0; r < 4; r++) {
            const long row = bm * 64 + wm * 32 + mt * 16 + quad * 4 + r;
#pragma unroll
            for (int nt = 0; nt < 4; nt++) {
                const long col = bn * 128 + wn * 64 + nt * 16 + l15;
                const float v = acc[mt][nt][r] + bv[nt];
                if (OUT_F16) ((_Float16*)Cout)[row * (long)N + col] = (_Float16)v;
                else         ((float*)Cout)[row * (long)N + col] = v;
            }
        }
    }
}

// ---------------------------------------------------------------------------
// Fused: RoPE on q,k -> Qh/Kh [h][s][96] (Q pre-scaled by SCALE*log2e, pads
// zeroed) + V transposed via LDS -> Vt[h][d][s]. Block = (64 seqs, 1 head).
__global__ __launch_bounds__(256)
void rope_repack_t(const _Float16* __restrict__ qkv,
                   const float* __restrict__ cosb,
                   const float* __restrict__ sinb,
                   _Float16* __restrict__ Qh,
                   _Float16* __restrict__ Kh,
                   _Float16* __restrict__ Vt) {
    const int s0 = blockIdx.x * 64;
    const int h  = blockIdx.y;
    __shared__ __align__(16) _Float16 Ts[64 * 88];
    const int tid = threadIdx.x;

    // stage V rows into LDS (transposed write later)
    for (int i = tid; i < 640; i += 256) {          // 64 rows x 10 chunks
        const int r = i / 10, c = (i - r * 10) * 8;
        *(half8*)&Ts[r * 88 + c] =
            *(const half8*)&qkv[(long)(s0 + r) * QKV_N + 2 * DIMM + h * HD + c];
    }

    // q,k rope: 64 rows x 5 chunks of 8 (d in [0,40))
    for (int i = tid; i < 320; i += 256) {
        const int r = i / 5, d = (i - r * 5) * 8;
        const _Float16* row = qkv + (long)(s0 + r) * QKV_N + h * HD;
        const half8 q0 = *(const half8*)&row[d];
        const half8 q1 = *(const half8*)&row[d + 40];
        const half8 k0 = *(const half8*)&row[DIMM + d];
        const half8 k1 = *(const half8*)&row[DIMM + d + 40];
        const float4 cA = *(const float4*)&cosb[(s0 + r) * HD + d];
        const float4 cB = *(const float4*)&cosb[(s0 + r) * HD + d + 4];
        const float4 sA = *(const float4*)&sinb[(s0 + r) * HD + d];
        const float4 sB = *(const float4*)&sinb[(s0 + r) * HD + d + 4];
        half8 qo0, qo1, ko0, ko1;
#pragma unroll
        for (int j = 0; j < 8; j++) {
            const float cj = (j < 4) ? cA[j] : cB[j - 4];
            const float sj = (j < 4) ? sA[j] : sB[j - 4];
            qo0[j] = (_Float16)(((float)q0[j] * cj - (float)q1[j] * sj) * QSCALE_LOG2E);
            qo1[j] = (_Float16)(((float)q1[j] * cj + (float)q0[j] * sj) * QSCALE_LOG2E);
            ko0[j] = (_Float16)((float)k0[j] * cj - (float)k1[j] * sj);
            ko1[j] = (_Float16)((float)k1[j] * cj + (float)k0[j] * sj);
        }
        const long o = ((long)h * SEQLEN + s0 + r) * HDP;
        *(half8*)&Qh[o + d]      = qo0;
        *(half8*)&Qh[o + d + 40] = qo1;
        *(half8*)&Kh[o + d]      = ko0;
        *(half8*)&Kh[o + d + 40] = ko1;
    }
    // zero pads d in [80,96)
    for (int i = tid; i < 128; i += 256) {
        const int r = i >> 1, off = HD + (i & 1) * 8;
        const long o = ((long)h * SEQLEN + s0 + r) * HDP + off;
        *(half8*)&Qh[o] = (half8)(_Float16)0.f;
        *(half8*)&Kh[o] = (half8)(_Float16)0.f;
    }
    __syncthreads();
    // transposed V out: 80 d-rows x 8 s-chunks
    for (int i = tid; i < 640; i += 256) {
        const int d = i >> 3, sc = (i & 7) * 8;
        half8 v;
#pragma unroll
        for (int j = 0; j < 8; j++) v[j] = Ts[(sc + j) * 88 + d];
        *(half8*)&Vt[((long)h * HD + d) * SEQLEN + s0 + sc] = v;
    }
}

// ---------------------------------------------------------------------------
// Flash attention v2, transposed dataflow, fixed-max base-2 softmax, split x4.
// 512-thread blocks: 8 waves x 16 q-rows = 128 q-rows/block; 64-key tiles.
//
// v2 changes vs v1 (theory: latency-bound staging + half-rate PV + addr VALU):
//  * T14 issue-early staging: each thread owns 3 fixed chunks of the K/V
//    tile (768 K-chunks + 640 V-chunks = 1408 = 512*2.75); global loads for
//    tile t+1 are issued BEFORE compute(t), only ds_writes sit between the
//    barriers. All chunk addressing hoisted out of the loop (no div/mod
//    per tile).
//  * PV uses mfma_16x16x32 (10 full-rate MFMA vs 20 half-rate 16x16x16).
//    P^T (key = ct*16+quad*4+r per lane) is repacked to the K=32 B-operand
//    order (key = quad*8+j) with v_cvt_pkrtz_f16_f32 packing + one
//    v_permlane32_swap + v_permlane16_swap per dword pair (l15/query index
//    is invariant under both swaps). V tile is plain d-major [80][72]
//    (36-dw stride: 2-way start banks = free; fragment scatter gone).
//  * LDS 24.8 KB; VGPR ~80 -> __launch_bounds__(512,6), 3 blocks/CU.
__global__ __launch_bounds__(512, 6)
void attn_kernel(const _Float16* __restrict__ Qh, const _Float16* __restrict__ Kh,
                 const _Float16* __restrict__ Vt,
                 _Float16* __restrict__ Ohat0, _Float16* __restrict__ Ohat1,
                 float* __restrict__ Lpart) {
    const int s0 = blockIdx.x * 128;
    const int h  = blockIdx.y;
    const int z  = blockIdx.z;
    __shared__ __align__(16) _Float16 Sb[VSOFF + 80 * VSTRIDE];   // 24.25 KB

    const int tid  = threadIdx.x;
    const int lane = tid & 63;
    const int wave = tid >> 6;
    const int l15  = lane & 15;
    const int quad = lane >> 4;

    const int zBeg = z * KVSPAN, zEnd = zBeg + KVSPAN;

    // Q fragments (persistent)
    const _Float16* Qg = Qh + ((long)h * SEQLEN + s0 + wave * 16 + l15) * HDP;
    half8 qf[3];
#pragma unroll
    for (int kk = 0; kk < 3; kk++)
        qf[kk] = *(const half8*)&Qg[kk * 32 + quad * 8];

    // ---- hoisted staging assignment: chunk c = tid + r*512 ----
    // c in [0,768): K chunk: row=c/12, col=(c%12)*8  -> Sb[row*104 + col]
    // c in [768,1408): V chunk v=c-768: d=v>>3, col=(v&7)*8 -> Sb[VSOFF+d*72+col]
    const _Float16* p0; const _Float16* p1; const _Float16* p2;
    int adv1, loff0, loff1, loff2;
    {
        const int r0 = tid / 12, c0 = tid - r0 * 12;            // r=0: always K
        p0 = Kh + ((long)h * SEQLEN + zBeg + r0) * HDP + c0 * 8;
        loff0 = r0 * KSTRIDE + c0 * 8;
        if (tid < 256) {                                        // r=1: K part
            const int r1 = (tid + 512) / 12, c1 = (tid + 512) - r1 * 12;
            p1 = Kh + ((long)h * SEQLEN + zBeg + r1) * HDP + c1 * 8;
            adv1 = 64 * HDP;
            loff1 = r1 * KSTRIDE + c1 * 8;
        } else {                                                // r=1: V part
            const int v = tid - 256, d = v >> 3, c = v & 7;     // d in [0,32)
            p1 = Vt + ((long)h * HD + d) * SEQLEN + zBeg + c * 8;
            adv1 = 64;
            loff1 = VSOFF + d * VSTRIDE + c * 8;
        }
        const int v2 = tid + 256, d2 = v2 >> 3, c2 = v2 & 7;    // r=2 (tid<384): V, d in [32,80)
        p2 = Vt + ((long)h * HD + d2) * SEQLEN + zBeg + c2 * 8;
        loff2 = VSOFF + d2 * VSTRIDE + c2 * 8;
    }

    // prologue: issue loads for first tile
    half8 rg0, rg1, rg2;
    rg0 = *(const half8*)p0; p0 += 64 * HDP;
    rg1 = *(const half8*)p1; p1 += adv1;
    if (tid < 384) { rg2 = *(const half8*)p2; p2 += 64; }

    f32x4 oaccT[5] = {};
    float l_acc = 0.f;

    for (int t0 = zBeg; t0 < zEnd; t0 += 64) {
        __syncthreads();                       // all waves done reading LDS
        *(half8*)&Sb[loff0] = rg0;             // (compiler waits loads here)
        *(half8*)&Sb[loff1] = rg1;
        if (tid < 384) *(half8*)&Sb[loff2] = rg2;
        if (t0 + 64 < zEnd) {                  // uniform: issue next tile early
            rg0 = *(const half8*)p0; p0 += 64 * HDP;
            rg1 = *(const half8*)p1; p1 += adv1;
            if (tid < 384) { rg2 = *(const half8*)p2; p2 += 64; }
        }
        __syncthreads();                       // LDS ready; loads in flight

        // S^T: 4 col-tiles of 16 keys (operands swapped: A=K, B=Q)
        f32x4 sa[4] = {};
        __builtin_amdgcn_s_setprio(1);
#pragma unroll
        for (int kk = 0; kk < 3; kk++)
#pragma unroll
            for (int ct = 0; ct < 4; ct++) {
                const half8 kf = *(const half8*)&Sb[(ct * 16 + l15) * KSTRIDE + kk * 32 + quad * 8];
                sa[ct] = mfma_16x16x32(kf, qf[kk], sa[ct]);
            }
        __builtin_amdgcn_s_setprio(0);

        // P^T = exp2(S^T); repack (key=ct*16+q*4+r) -> (key=q*8+j) for the
        // 16x16x32 B-operand: cvt_pkrtz pairs, then permlane32+16 swaps.
        half8 Bf[2];
#pragma unroll
        for (int pr = 0; pr < 2; pr++) {
            const f32x4 sA = sa[2 * pr], sB = sa[2 * pr + 1];
            const float eA0 = EXP2F(sA[0]), eA1 = EXP2F(sA[1]);
            const float eA2 = EXP2F(sA[2]), eA3 = EXP2F(sA[3]);
            const float eB0 = EXP2F(sB[0]), eB1 = EXP2F(sB[1]);
            const float eB2 = EXP2F(sB[2]), eB3 = EXP2F(sB[3]);
            l_acc += ((eA0 + eA1) + (eA2 + eA3)) + ((eB0 + eB1) + (eB2 + eB3));
            int x0 = __builtin_bit_cast(int, __builtin_amdgcn_cvt_pkrtz(eA0, eA1));
            int x1 = __builtin_bit_cast(int, __builtin_amdgcn_cvt_pkrtz(eA2, eA3));
            int y0 = __builtin_bit_cast(int, __builtin_amdgcn_cvt_pkrtz(eB0, eB1));
            int y1 = __builtin_bit_cast(int, __builtin_amdgcn_cvt_pkrtz(eB2, eB3));
            // x:{ct=2pr}, y:{ct=2pr+1}; after swap32: x={x_lo,y_lo}, y={x_hi,y_hi};
            // after swap16: x=u (rows 0 of each), y=w (rows 1 of each).
            asm("v_permlane32_swap_b32 %0, %1" : "+v"(x0), "+v"(y0));
            asm("v_permlane16_swap_b32 %0, %1" : "+v"(x0), "+v"(y0));
            asm("v_permlane32_swap_b32 %0, %1" : "+v"(x1), "+v"(y1));
            asm("v_permlane16_swap_b32 %0, %1" : "+v"(x1), "+v"(y1));
            const int4v bi = {x0, x1, y0, y1};   // halves j0..7 = keys q*8+0..7
            Bf[pr] = __builtin_bit_cast(half8, bi);
        }

        // O^T += V^T * P^T : 2 x 16x16x32 per nt (keys 0..31, 32..63)
        __builtin_amdgcn_s_setprio(1);
#pragma unroll
        for (int nt = 0; nt < 5; nt++) {
            const half8 va0 = *(const half8*)&Sb[VSOFF + (nt * 16 + l15) * VSTRIDE + quad * 8];
            const half8 va1 = *(const half8*)&Sb[VSOFF + (nt * 16 + l15) * VSTRIDE + 32 + quad * 8];
            oaccT[nt] = mfma_16x16x32(va0, Bf[0], oaccT[nt]);
            oaccT[nt] = mfma_16x16x32(va1, Bf[1], oaccT[nt]);
        }
        __builtin_amdgcn_s_setprio(0);
    }

    // l: sum the 4 quads holding this query's key-chunks
    l_acc += __shfl_xor(l_acc, 16);
    l_acc += __shfl_xor(l_acc, 32);
    const float inv = 1.0f / l_acc;

    // partials: z 0,1 -> Ohat0 region, z 2,3 -> Ohat1 region
    _Float16* Oz = (z < 2) ? Ohat0 : Ohat1;
    const long obase = ((long)(z & 1) * NHEADS + h) * SEQLEN;
    const long lbase = ((long)z * NHEADS + h) * SEQLEN;
    const long row = s0 + wave * 16 + l15;           // this lane's query
#pragma unroll
    for (int nt = 0; nt < 5; nt++) {
        half4 o;
#pragma unroll
        for (int r = 0; r < 4; r++) o[r] = (_Float16)(oaccT[nt][r] * inv);
        *(half4*)&Oz[(obase + row) * HD + nt * 16 + quad * 4] = o;
    }
    if (quad == 0)
        Lpart[lbase + row] = l_acc;
}

// ---------------------------------------------------------------------------
// out = sum_z Ohat_z * l_z / sum_z l_z  -> attnb f16 [s][h*80+d]
__global__ __launch_bounds__(256)
void attn_combine(const _Float16* __restrict__ Ohat0,
                  const _Float16* __restrict__ Ohat1,
                  const float* __restrict__ Lp,
                  _Float16* __restrict__ attnb) {
    const int i = blockIdx.x * 256 + threadIdx.x;
    if (i >= SEQLEN * DIMM / 4) return;
    const int flat = i * 4;
    const int s = flat / DIMM;
    const int rem = flat - s * DIMM;
    const int h = rem / HD;
    const int d = rem - h * HD;
    float l[NSPLIT], lsum = 0.f;
#pragma unroll
    for (int zi = 0; zi < NSPLIT; zi++) {
        l[zi] = Lp[((long)zi * NHEADS + h) * SEQLEN + s];
        lsum += l[zi];
    }
    const float invl = 1.0f / lsum;
    float acc[4] = {0.f, 0.f, 0.f, 0.f};
#pragma unroll
    for (int zi = 0; zi < NSPLIT; zi++) {
        const _Float16* Oz = (zi < 2) ? Ohat0 : Ohat1;
        const long obase = ((long)(zi & 1) * NHEADS + h) * SEQLEN;
        const half4 o = *(const half4*)&Oz[(obase + s) * HD + d];
        const float w = l[zi] * invl;
#pragma unroll
        for (int j = 0; j < 4; j++) acc[j] += (float)o[j] * w;
    }
    half4 o;
#pragma unroll
    for (int j = 0; j < 4; j++) o[j] = (_Float16)acc[j];
    *(half4*)&attnb[(long)s * DIMM + rem] = o;
}

// ---------------------------------------------------------------------------
extern "C" void kernel_launch(void* const* d_in, const int* in_sizes, int n_in,
                              void* d_out, int out_size, void* d_ws, size_t ws_size,
                              hipStream_t stream) {
    const float* hs     = (const float*)d_in[0];
    // d_in[1] = cu_seqlens [0, 2048] — reference does no masking; unused.
    const float* cosb   = (const float*)d_in[2];
    const float* sinb   = (const float*)d_in[3];
    const float* w_qkv  = (const float*)d_in[4];
    const float* b_qkv  = (const float*)d_in[5];
    const float* w_proj = (const float*)d_in[6];
    const float* b_proj = (const float*)d_in[7];
    float* out = (float*)d_out;

    _Float16* hsb    = (_Float16*)d_ws;                       // 2048*1280
    _Float16* wqkvb  = hsb    + (long)SEQLEN * DIMM;          // 3840*1280
    _Float16* wprojb = wqkvb  + (long)QKV_N * DIMM;           // 1280*1280
    _Float16* qkv    = wprojb + (long)DIMM * DIMM;            // 2048*3840
    _Float16* Qh     = qkv    + (long)SEQLEN * QKV_N;         // 16*2048*96
    _Float16* Kh     = Qh     + (long)NHEADS * SEQLEN * HDP;
    _Float16* Vtb    = Kh     + (long)NHEADS * SEQLEN * HDP;  // 16*80*2048
    _Float16* attnb  = Vtb    + (long)NHEADS * HD * SEQLEN;   // 2048*1280

    // attention partials alias DEAD regions during attention:
    //   Ohat0 (z=0,1): hsb+wqkvb region (15.07 MB) — dead after QKV GEMM.
    //   Ohat1 (z=2,3): qkv region (15.73 MB) — dead after rope_repack_t.
    _Float16* Ohat0  = (_Float16*)d_ws;
    float*    LpartB = (float*)(Ohat0 + (long)2 * NHEADS * SEQLEN * HD);
    _Float16* Ohat1  = qkv;

    {
        const int ntot = (SEQLEN * DIMM + QKV_N * DIMM + DIMM * DIMM) / 4;
        cast_all<<<(ntot + 255) / 256, 256, 0, stream>>>(
            hs, w_qkv, w_proj, hsb, wqkvb, wprojb);
    }

    gemm_bt64<true><<<dim3(SEQLEN / 64, QKV_N / 128), 256, 0, stream>>>(
        hsb, wqkvb, b_qkv, qkv, SEQLEN, QKV_N, DIMM);

    rope_repack_t<<<dim3(SEQLEN / 64, NHEADS), 256, 0, stream>>>(
        qkv, cosb, sinb, Qh, Kh, Vtb);

    attn_kernel<<<dim3(SEQLEN / 128, NHEADS, NSPLIT), 512, 0, stream>>>(
        Qh, Kh, Vtb, Ohat0, Ohat1, LpartB);

    attn_combine<<<(SEQLEN * DIMM / 4 + 255) / 256, 256, 0, stream>>>(
        Ohat0, Ohat1, LpartB, attnb);

    gemm_bt64<false><<<dim3(SEQLEN / 64, DIMM / 128), 256, 0, stream>>>(
        attnb, wprojb, b_proj, out, SEQLEN, DIMM, DIMM);
}

// Round 2
// 200.417 us; speedup vs baseline: 1.1219x; 1.1219x over previous
//
#include <hip/hip_runtime.h>

// ---------------------------------------------------------------------------
// SimpleVisionAttention on MI355X (gfx950)
// S=2048, DIM=1280 (16 heads x 80), fp32 in/out, f16 MFMA internally.
//
// Pipeline:
//   K1  fused cast fp32 -> f16   (hs, w_qkv, w_proj)
//   K2  QKV GEMM  64x128 tiles, BK=64 dual-panel (half the barriers of BK=32)
//   K3  fused RoPE + repack Qh/Kh [h][s][80] (dense) + V transpose -> Vt[h][d][s]
//   K4  flash attention, transposed dataflow (S^T->P^T in regs), fixed-max
//       base-2 softmax, KV-split x4, fragment-major V (stride 24).
//       v3: hoisted per-lane staging offsets (no per-tile div/mod), loads
//       issued before barrier-1 (short reg live range — v2's cross-compute
//       hold spilled to scratch and doubled WRITE_SIZE), dense K=80 QK
//       (2x K32 + 1x K16 MFMA), cvt_pkrtz P-pack + v_dot2 l-accum
//       (replaces 16-deep serial f32 add chain), setprio around MFMA.
//   K4b combine 4 partials (weighted by per-split l)
//   K5  proj GEMM 64x128 tiles, BK=64 dual-panel
// ---------------------------------------------------------------------------

#define SEQLEN   2048
#define DIMM     1280
#define NHEADS   16
#define HD       80
#define QKV_N    3840
#define NSPLIT   4
#define KVSPAN   (SEQLEN / NSPLIT)
// SCALE * log2(e) folded into Q at rope time; softmax done in base-2.
#define QSCALE_LOG2E 0.16130083587064776f   // 80^-0.5 * 1.4426950408889634

#define KSTRIDE  88   // K-tile row stride (44 dw): 8-bank spread, balanced b128
#define VFSTRIDE 24   // VF row stride (12 dw): balanced lane->bank spread

// device base-2 exp: v_exp_f32 (NOT __exp2f — collides with glibc math.h)
#define EXP2F(x) __builtin_amdgcn_exp2f(x)

// async global->LDS, 16B per lane; LDS dest must be waveBase + lane*16
#define GLD16(gptr, lptr)                                                      \
    __builtin_amdgcn_global_load_lds(                                          \
        (const __attribute__((address_space(1))) void*)(gptr),                 \
        (__attribute__((address_space(3))) void*)(lptr), 16, 0, 0)

typedef float f32x4 __attribute__((ext_vector_type(4)));
typedef _Float16 half8 __attribute__((ext_vector_type(8)));
typedef _Float16 half4 __attribute__((ext_vector_type(4)));
typedef _Float16 half2v __attribute__((ext_vector_type(2)));

static __device__ __forceinline__ f32x4 mfma_16x16x32(half8 a, half8 b, f32x4 c) {
    return __builtin_amdgcn_mfma_f32_16x16x32_f16(a, b, c, 0, 0, 0);
}
// NOTE: legacy K=16 shape is spelled WITHOUT the underscore: ...16x16x16f16
static __device__ __forceinline__ f32x4 mfma_16x16x16(half4 a, half4 b, f32x4 c) {
    return __builtin_amdgcn_mfma_f32_16x16x16f16(a, b, c, 0, 0, 0);
}
static __device__ __forceinline__ half4 lo4(half8 v) {
    return __builtin_shufflevector(v, v, 0, 1, 2, 3);
}
static __device__ __forceinline__ half4 hi4(half8 v) {
    return __builtin_shufflevector(v, v, 4, 5, 6, 7);
}

// ---------------------------------------------------------------------------
// One fused cast kernel for the three fp32->f16 conversions.
__global__ __launch_bounds__(256)
void cast_all(const float* __restrict__ hs, const float* __restrict__ wq,
              const float* __restrict__ wp, _Float16* __restrict__ dhs,
              _Float16* __restrict__ dwq, _Float16* __restrict__ dwp) {
    const int n1 = SEQLEN * DIMM / 4, n2 = QKV_N * DIMM / 4, n3 = DIMM * DIMM / 4;
    int i = blockIdx.x * 256 + threadIdx.x;
    const float4* src; half4* dst; int j;
    if (i < n1)           { src = (const float4*)hs; dst = (half4*)dhs; j = i; }
    else if (i < n1 + n2) { src = (const float4*)wq; dst = (half4*)dwq; j = i - n1; }
    else if (i < n1 + n2 + n3) { src = (const float4*)wp; dst = (half4*)dwp; j = i - n1 - n2; }
    else return;
    const float4 v = src[j];
    half4 h;
    h.x = (_Float16)v.x; h.y = (_Float16)v.y;
    h.z = (_Float16)v.z; h.w = (_Float16)v.w;
    dst[j] = h;
}

// ---------------------------------------------------------------------------
// C[m][n] = sum_k A[m][k] * B[n][k] + bias[n]
// A: M x K f16 row-major, B: N x K f16 row-major (i.e. B^T layout).
// 64x128 block tile, 4 waves 2x2 (each 32x64, 2x4 mfma tiles).
// BK=64 as TWO BK=32 PANELS: keeps the LDS row stride at 32 halves (a flat
// 64-stride would put lane-strided ds_reads on one bank = 16-way conflict,
// and global_load_lds forbids padding). Halves barrier count vs BK=32:
// 20 K-iters x 2 barriers, 16 MFMA + 6 GLD16 + 12 ds_read_b128 per iter.
template<bool OUT_F16>
__global__ __launch_bounds__(256, 2)
void gemm_bt64(const _Float16* __restrict__ A, const _Float16* __restrict__ B,
               const float* __restrict__ bias, void* __restrict__ Cout,
               int M, int N, int K) {
    __shared__ __align__(16) _Float16 As[2][64 * 32];    // 8 KB
    __shared__ __align__(16) _Float16 Bs[2][128 * 32];   // 16 KB
    const int tid  = threadIdx.x;
    const int lane = tid & 63;
    const int wave = tid >> 6;
    const int l15  = lane & 15;
    const int quad = lane >> 4;
    const int wm   = wave & 1;
    const int wn   = wave >> 1;
    const long bm = blockIdx.x, bn = blockIdx.y;

    const _Float16* Ag = A + bm * 64 * (long)K;
    const _Float16* Bg = B + bn * 128 * (long)K;

    const int srow = lane >> 2;            // 0..15 within chunk
    const int scol = (lane & 3) * 8;       // halves
    f32x4 acc[2][4] = {};

    for (int k0 = 0; k0 < K; k0 += 64) {
        __syncthreads();
#pragma unroll
        for (int p = 0; p < 2; p++) {
            const int kp = k0 + p * 32;
            const long arow = 16 * wave + srow;
            GLD16(Ag + arow * K + kp + scol, &As[p][512 * wave + lane * 8]);
#pragma unroll
            for (int cc = 0; cc < 2; cc++) {
                const int c = wave + cc * 4;
                const long brow = 16 * c + srow;
                GLD16(Bg + brow * K + kp + scol, &Bs[p][512 * c + lane * 8]);
            }
        }
        __syncthreads();
#pragma unroll
        for (int p = 0; p < 2; p++) {
            half8 af[2], bf[4];
#pragma unroll
            for (int t = 0; t < 2; t++)
                af[t] = *(const half8*)&As[p][(wm * 32 + t * 16 + l15) * 32 + quad * 8];
#pragma unroll
            for (int t = 0; t < 4; t++)
                bf[t] = *(const half8*)&Bs[p][(wn * 64 + t * 16 + l15) * 32 + quad * 8];
#pragma unroll
            for (int mt = 0; mt < 2; mt++)
#pragma unroll
                for (int nt = 0; nt < 4; nt++)
                    acc[mt][nt] = mfma_16x16x32(af[mt], bf[nt], acc[mt][nt]);
        }
    }

    float bv[4];
#pragma unroll
    for (int nt = 0; nt < 4; nt++)
        bv[nt] = bias[bn * 128 + wn * 64 + nt * 16 + l15];

#pragma unroll
    for (int mt = 0; mt < 2; mt++) {
#pragma unroll
        for (int r = 0; r < 4; r++) {
            const long row = bm * 64 + wm * 32 + mt * 16 + quad * 4 + r;
#pragma unroll
            for (int nt = 0; nt < 4; nt++) {
                const long col = bn * 128 + wn * 64 + nt * 16 + l15;
                const float v = acc[mt][nt][r] + bv[nt];
                if (OUT_F16) ((_Float16*)Cout)[row * (long)N + col] = (_Float16)v;
                else         ((float*)Cout)[row * (long)N + col] = v;
            }
        }
    }
}

// ---------------------------------------------------------------------------
// Fused: RoPE on q,k -> Qh/Kh [h][s][80] dense (Q pre-scaled by SCALE*log2e)
// + V transposed via LDS -> Vt[h][d][s]. Block = (64 seqs, 1 head).
__global__ __launch_bounds__(256)
void rope_repack_t(const _Float16* __restrict__ qkv,
                   const float* __restrict__ cosb,
                   const float* __restrict__ sinb,
                   _Float16* __restrict__ Qh,
                   _Float16* __restrict__ Kh,
                   _Float16* __restrict__ Vt) {
    const int s0 = blockIdx.x * 64;
    const int h  = blockIdx.y;
    __shared__ __align__(16) _Float16 Ts[64 * 88];
    const int tid = threadIdx.x;

    // stage V rows into LDS (transposed write later)
    for (int i = tid; i < 640; i += 256) {          // 64 rows x 10 chunks
        const int r = i / 10, c = (i - r * 10) * 8;
        *(half8*)&Ts[r * 88 + c] =
            *(const half8*)&qkv[(long)(s0 + r) * QKV_N + 2 * DIMM + h * HD + c];
    }

    // q,k rope: 64 rows x 5 chunks of 8 (d in [0,40))
    for (int i = tid; i < 320; i += 256) {
        const int r = i / 5, d = (i - r * 5) * 8;
        const _Float16* row = qkv + (long)(s0 + r) * QKV_N + h * HD;
        const half8 q0 = *(const half8*)&row[d];
        const half8 q1 = *(const half8*)&row[d + 40];
        const half8 k0 = *(const half8*)&row[DIMM + d];
        const half8 k1 = *(const half8*)&row[DIMM + d + 40];
        const float4 cA = *(const float4*)&cosb[(s0 + r) * HD + d];
        const float4 cB = *(const float4*)&cosb[(s0 + r) * HD + d + 4];
        const float4 sA = *(const float4*)&sinb[(s0 + r) * HD + d];
        const float4 sB = *(const float4*)&sinb[(s0 + r) * HD + d + 4];
        half8 qo0, qo1, ko0, ko1;
#pragma unroll
        for (int j = 0; j < 8; j++) {
            const float cj = (j < 4) ? cA[j] : cB[j - 4];
            const float sj = (j < 4) ? sA[j] : sB[j - 4];
            qo0[j] = (_Float16)(((float)q0[j] * cj - (float)q1[j] * sj) * QSCALE_LOG2E);
            qo1[j] = (_Float16)(((float)q1[j] * cj + (float)q0[j] * sj) * QSCALE_LOG2E);
            ko0[j] = (_Float16)((float)k0[j] * cj - (float)k1[j] * sj);
            ko1[j] = (_Float16)((float)k1[j] * cj + (float)k0[j] * sj);
        }
        const long o = ((long)h * SEQLEN + s0 + r) * HD;
        *(half8*)&Qh[o + d]      = qo0;
        *(half8*)&Qh[o + d + 40] = qo1;
        *(half8*)&Kh[o + d]      = ko0;
        *(half8*)&Kh[o + d + 40] = ko1;
    }
    __syncthreads();
    // transposed V out: 80 d-rows x 8 s-chunks
    for (int i = tid; i < 640; i += 256) {
        const int d = i >> 3, sc = (i & 7) * 8;
        half8 v;
#pragma unroll
        for (int j = 0; j < 8; j++) v[j] = Ts[(sc + j) * 88 + d];
        *(half8*)&Vt[((long)h * HD + d) * SEQLEN + s0 + sc] = v;
    }
}

// ---------------------------------------------------------------------------
// Flash attention v3, transposed dataflow, fixed-max base-2 softmax, split x4.
// 512-thread blocks: 8 waves x 16 q-rows = 128 q-rows/block; 64-key tiles.
// S^T = mfma(K, Q) with dense K=80 (2x K32 + 1x K16); P^T = exp2(S^T) packed
// via cvt_pkrtz straight into the PV 16x16x16 B-operand; l accumulated with
// v_dot2_f32_f16 into two independent accumulators (no serial add chain).
// Staging: per-lane 32-bit offsets hoisted to init; loads for tile t issued
// BEFORE barrier-1 (overlaps other waves' tile t-1 compute; registers live
// across one barrier only — v2's cross-compute hold spilled to scratch).
// LDS 26 KB -> 4 blocks/CU, grid 1024 exactly resident.
__global__ __launch_bounds__(512, 8)
void attn_kernel(const _Float16* __restrict__ Qh, const _Float16* __restrict__ Kh,
                 const _Float16* __restrict__ Vt,
                 _Float16* __restrict__ Ohat0, _Float16* __restrict__ Ohat1,
                 float* __restrict__ Lpart) {
    const int s0 = blockIdx.x * 128;
    const int h  = blockIdx.y;
    const int z  = blockIdx.z;
    __shared__ __align__(16) _Float16 Ks[64 * KSTRIDE];        // 11.0 KB
    __shared__ __align__(16) _Float16 VF[5 * 64 * VFSTRIDE];   // 15.0 KB

    const int tid  = threadIdx.x;
    const int lane = tid & 63;
    const int wave = tid >> 6;
    const int l15  = lane & 15;
    const int quad = lane >> 4;

    const int zBeg = z * KVSPAN, zEnd = zBeg + KVSPAN;

    // Q fragments (persistent): dense 80 = 2x half8 + 1x half4
    const _Float16* Qg = Qh + ((long)h * SEQLEN + s0 + wave * 16 + l15) * HD;
    const half8 qf0 = *(const half8*)&Qg[quad * 8];
    const half8 qf1 = *(const half8*)&Qg[32 + quad * 8];
    const half4 qf2 = *(const half4*)&Qg[64 + quad * 4];

    // ---- hoisted staging assignment (all div/mod at init only) ----
    // 640 K chunks (64 rows x 10) + 640 V chunks (80 d-rows x 8) = 1280:
    //  slot A (all 512):   K chunks [0,512)
    //  slot B (tid<128):   K chunks [512,640)   | (tid>=128): V chunks [0,384)
    //  slot C (tid<256):   V chunks [384,640)
    // Branch boundaries are wave-aligned (128, 256).
    int offA, lA, offB, lB0, lB1 = 0, offC = 0, lC0 = 0, lC1 = 0;
    {
        const int rA = tid / 10, cA = (tid - rA * 10) * 8;
        offA = rA * HD + cA;
        lA   = rA * KSTRIDE + cA;
        if (tid < 128) {
            const int cB = tid + 512;
            const int rB = cB / 10, ccB = (cB - rB * 10) * 8;
            offB = rB * HD + ccB;
            lB0  = rB * KSTRIDE + ccB;
        } else {
            const int v = tid - 128, d = v >> 3, c8 = (v & 7) * 8;
            offB = d * SEQLEN + c8;
            const int nt = d >> 4, ld = d & 15, ct = c8 >> 4, qb = (c8 & 15) >> 2;
            lB0 = (nt * 64 + qb * 16 + ld) * VFSTRIDE + ct * 4;
            lB1 = (nt * 64 + (qb + 1) * 16 + ld) * VFSTRIDE + ct * 4;
        }
        if (tid < 256) {
            const int v = tid + 384, d = v >> 3, c8 = (v & 7) * 8;
            offC = d * SEQLEN + c8;
            const int nt = d >> 4, ld = d & 15, ct = c8 >> 4, qb = (c8 & 15) >> 2;
            lC0 = (nt * 64 + qb * 16 + ld) * VFSTRIDE + ct * 4;
            lC1 = (nt * 64 + (qb + 1) * 16 + ld) * VFSTRIDE + ct * 4;
        }
    }
    const _Float16* KzBase = Kh + ((long)h * SEQLEN + zBeg) * HD;
    const _Float16* VzBase = Vt + (long)h * HD * SEQLEN + zBeg;

    f32x4 oaccT[5] = {};
    float la0 = 0.f, la1 = 0.f;
    const half2v ones2 = {(_Float16)1.f, (_Float16)1.f};

    for (int t0 = zBeg; t0 < zEnd; t0 += 64) {
        // issue this tile's loads BEFORE the barrier: they fly while other
        // waves finish the previous tile's compute.
        const _Float16* KzT = KzBase + (long)(t0 - zBeg) * HD;
        const _Float16* VzT = VzBase + (t0 - zBeg);
        const half8 a = *(const half8*)(KzT + offA);
        half8 b;
        if (tid < 128) b = *(const half8*)(KzT + offB);
        else           b = *(const half8*)(VzT + offB);
        half8 cv = {};
        if (tid < 256) cv = *(const half8*)(VzT + offC);

        __syncthreads();                       // all waves done reading LDS
        *(half8*)&Ks[lA] = a;
        if (tid < 128) { *(half8*)&Ks[lB0] = b; }
        else {
            *(half4*)&VF[lB0] = lo4(b);
            *(half4*)&VF[lB1] = hi4(b);
        }
        if (tid < 256) {
            *(half4*)&VF[lC0] = lo4(cv);
            *(half4*)&VF[lC1] = hi4(cv);
        }
        __syncthreads();                       // LDS ready

        // S^T: 4 col-tiles of 16 keys (operands swapped: A=K, B=Q), K=80 dense
        f32x4 sa[4] = {};
        __builtin_amdgcn_s_setprio(1);
#pragma unroll
        for (int ct = 0; ct < 4; ct++) {
            const int kb = (ct * 16 + l15) * KSTRIDE;
            const half8 kf0 = *(const half8*)&Ks[kb + quad * 8];
            const half8 kf1 = *(const half8*)&Ks[kb + 32 + quad * 8];
            sa[ct] = mfma_16x16x32(kf0, qf0, sa[ct]);
            sa[ct] = mfma_16x16x32(kf1, qf1, sa[ct]);
            const half4 kf2 = *(const half4*)&Ks[kb + 64 + quad * 4];
            sa[ct] = mfma_16x16x16(kf2, qf2, sa[ct]);
        }
        __builtin_amdgcn_s_setprio(0);

        // P^T = exp2(S^T): cvt_pkrtz pairs feed both the PV B-operand and
        // the l-accumulators (v_dot2 with ones; two independent chains).
        half4 pb[4];
#pragma unroll
        for (int ct = 0; ct < 4; ct++) {
            const float e0 = EXP2F(sa[ct][0]);
            const float e1 = EXP2F(sa[ct][1]);
            const float e2 = EXP2F(sa[ct][2]);
            const float e3 = EXP2F(sa[ct][3]);
            const half2v p01 = __builtin_bit_cast(half2v, __builtin_amdgcn_cvt_pkrtz(e0, e1));
            const half2v p23 = __builtin_bit_cast(half2v, __builtin_amdgcn_cvt_pkrtz(e2, e3));
            la0 = __builtin_amdgcn_fdot2(p01, ones2, la0, false);
            la1 = __builtin_amdgcn_fdot2(p23, ones2, la1, false);
            pb[ct] = __builtin_shufflevector(p01, p23, 0, 1, 2, 3);
        }

        // O^T += V^T * P^T : 2 lane-contiguous half8 reads per nt
        __builtin_amdgcn_s_setprio(1);
#pragma unroll
        for (int nt = 0; nt < 5; nt++) {
            const half8 va = *(const half8*)&VF[(nt * 64 + lane) * VFSTRIDE];
            const half8 vb = *(const half8*)&VF[(nt * 64 + lane) * VFSTRIDE + 8];
            oaccT[nt] = mfma_16x16x16(lo4(va), pb[0], oaccT[nt]);
            oaccT[nt] = mfma_16x16x16(hi4(va), pb[1], oaccT[nt]);
            oaccT[nt] = mfma_16x16x16(lo4(vb), pb[2], oaccT[nt]);
            oaccT[nt] = mfma_16x16x16(hi4(vb), pb[3], oaccT[nt]);
        }
        __builtin_amdgcn_s_setprio(0);
    }

    // l: sum the 4 quads holding this query's key-chunks
    float l_acc = la0 + la1;
    l_acc += __shfl_xor(l_acc, 16);
    l_acc += __shfl_xor(l_acc, 32);
    const float inv = 1.0f / l_acc;

    // partials: z 0,1 -> Ohat0 region, z 2,3 -> Ohat1 region
    _Float16* Oz = (z < 2) ? Ohat0 : Ohat1;
    const long obase = ((long)(z & 1) * NHEADS + h) * SEQLEN;
    const long lbase = ((long)z * NHEADS + h) * SEQLEN;
    const long row = s0 + wave * 16 + l15;           // this lane's query
#pragma unroll
    for (int nt = 0; nt < 5; nt++) {
        half4 o;
#pragma unroll
        for (int r = 0; r < 4; r++) o[r] = (_Float16)(oaccT[nt][r] * inv);
        *(half4*)&Oz[(obase + row) * HD + nt * 16 + quad * 4] = o;
    }
    if (quad == 0)
        Lpart[lbase + row] = l_acc;
}

// ---------------------------------------------------------------------------
// out = sum_z Ohat_z * l_z / sum_z l_z  -> attnb f16 [s][h*80+d]
__global__ __launch_bounds__(256)
void attn_combine(const _Float16* __restrict__ Ohat0,
                  const _Float16* __restrict__ Ohat1,
                  const float* __restrict__ Lp,
                  _Float16* __restrict__ attnb) {
    const int i = blockIdx.x * 256 + threadIdx.x;
    if (i >= SEQLEN * DIMM / 4) return;
    const int flat = i * 4;
    const int s = flat / DIMM;
    const int rem = flat - s * DIMM;
    const int h = rem / HD;
    const int d = rem - h * HD;
    float l[NSPLIT], lsum = 0.f;
#pragma unroll
    for (int zi = 0; zi < NSPLIT; zi++) {
        l[zi] = Lp[((long)zi * NHEADS + h) * SEQLEN + s];
        lsum += l[zi];
    }
    const float invl = 1.0f / lsum;
    float acc[4] = {0.f, 0.f, 0.f, 0.f};
#pragma unroll
    for (int zi = 0; zi < NSPLIT; zi++) {
        const _Float16* Oz = (zi < 2) ? Ohat0 : Ohat1;
        const long obase = ((long)(zi & 1) * NHEADS + h) * SEQLEN;
        const half4 o = *(const half4*)&Oz[(obase + s) * HD + d];
        const float w = l[zi] * invl;
#pragma unroll
        for (int j = 0; j < 4; j++) acc[j] += (float)o[j] * w;
    }
    half4 o;
#pragma unroll
    for (int j = 0; j < 4; j++) o[j] = (_Float16)acc[j];
    *(half4*)&attnb[(long)s * DIMM + rem] = o;
}

// ---------------------------------------------------------------------------
extern "C" void kernel_launch(void* const* d_in, const int* in_sizes, int n_in,
                              void* d_out, int out_size, void* d_ws, size_t ws_size,
                              hipStream_t stream) {
    const float* hs     = (const float*)d_in[0];
    // d_in[1] = cu_seqlens [0, 2048] — reference does no masking; unused.
    const float* cosb   = (const float*)d_in[2];
    const float* sinb   = (const float*)d_in[3];
    const float* w_qkv  = (const float*)d_in[4];
    const float* b_qkv  = (const float*)d_in[5];
    const float* w_proj = (const float*)d_in[6];
    const float* b_proj = (const float*)d_in[7];
    float* out = (float*)d_out;

    _Float16* hsb    = (_Float16*)d_ws;                       // 2048*1280
    _Float16* wqkvb  = hsb    + (long)SEQLEN * DIMM;          // 3840*1280
    _Float16* wprojb = wqkvb  + (long)QKV_N * DIMM;           // 1280*1280
    _Float16* qkv    = wprojb + (long)DIMM * DIMM;            // 2048*3840
    _Float16* Qh     = qkv    + (long)SEQLEN * QKV_N;         // 16*2048*80
    _Float16* Kh     = Qh     + (long)NHEADS * SEQLEN * HD;
    _Float16* Vtb    = Kh     + (long)NHEADS * SEQLEN * HD;   // 16*80*2048
    _Float16* attnb  = Vtb    + (long)NHEADS * HD * SEQLEN;   // 2048*1280

    // attention partials alias DEAD regions during attention:
    //   Ohat0 (z=0,1): hsb+wqkvb region (15.07 MB) — dead after QKV GEMM.
    //   Ohat1 (z=2,3): qkv region (15.73 MB) — dead after rope_repack_t.
    _Float16* Ohat0  = (_Float16*)d_ws;
    float*    LpartB = (float*)(Ohat0 + (long)2 * NHEADS * SEQLEN * HD);
    _Float16* Ohat1  = qkv;

    {
        const int ntot = (SEQLEN * DIMM + QKV_N * DIMM + DIMM * DIMM) / 4;
        cast_all<<<(ntot + 255) / 256, 256, 0, stream>>>(
            hs, w_qkv, w_proj, hsb, wqkvb, wprojb);
    }

    gemm_bt64<true><<<dim3(SEQLEN / 64, QKV_N / 128), 256, 0, stream>>>(
        hsb, wqkvb, b_qkv, qkv, SEQLEN, QKV_N, DIMM);

    rope_repack_t<<<dim3(SEQLEN / 64, NHEADS), 256, 0, stream>>>(
        qkv, cosb, sinb, Qh, Kh, Vtb);

    attn_kernel<<<dim3(SEQLEN / 128, NHEADS, NSPLIT), 512, 0, stream>>>(
        Qh, Kh, Vtb, Ohat0, Ohat1, LpartB);

    attn_combine<<<(SEQLEN * DIMM / 4 + 255) / 256, 256, 0, stream>>>(
        Ohat0, Ohat1, LpartB, attnb);

    gemm_bt64<false><<<dim3(SEQLEN / 64, DIMM / 128), 256, 0, stream>>>(
        attnb, wprojb, b_proj, out, SEQLEN, DIMM, DIMM);
}

// Round 5
// 187.576 us; speedup vs baseline: 1.1987x; 1.0685x over previous
//
#include <hip/hip_runtime.h>

// ---------------------------------------------------------------------------
// SimpleVisionAttention on MI355X (gfx950)
// S=2048, DIM=1280 (16 heads x 80), fp32 in/out, f16 MFMA internally.
//
// Pipeline:
//   K1  fused cast fp32 -> f16   (hs, w_qkv, w_proj)
//   K2  QKV GEMM  128x128 tiles, 8 waves, BK=64 dual-panel (v4: retiled from
//       64x128 — 250 staged B/MFMA vs 375, toward the measured 128^2 regime)
//   K3  fused RoPE + repack Qh/Kh [h][s][80] (dense) + V transpose -> Vt[h][d][s]
//   K4  flash attention. v4: 32 q-rows per wave (two Q fragments sharing every
//       K/V LDS read — LDS read traffic per unit work HALVES; it was ~45% of
//       kernel time: 8 waves x 20.5 KB/tile all reading the full tile).
//       Keeps v3's proven 2-barrier loop, hoisted staging, dense K=80 QK,
//       cvt_pkrtz P-pack + v_dot2 l-accum, setprio.
//   K4b combine 4 partials (weighted by per-split l)
//   K5  proj GEMM 64x128 tiles (128^2 would leave 96 CUs idle: grid 160)
//
// (v4 fix: staging offset vars renamed dsA/dsB0/... — previous submission
// had `int lA` colliding with the epilogue's `float lA`.)
// ---------------------------------------------------------------------------

#define SEQLEN   2048
#define DIMM     1280
#define NHEADS   16
#define HD       80
#define QKV_N    3840
#define NSPLIT   4
#define KVSPAN   (SEQLEN / NSPLIT)
// SCALE * log2(e) folded into Q at rope time; softmax done in base-2.
#define QSCALE_LOG2E 0.16130083587064776f   // 80^-0.5 * 1.4426950408889634

#define KSTRIDE  88   // K-tile row stride (44 dw): 8-bank spread, balanced b128
#define VFSTRIDE 24   // VF row stride (12 dw): balanced lane->bank spread

// device base-2 exp: v_exp_f32 (NOT __exp2f — collides with glibc math.h)
#define EXP2F(x) __builtin_amdgcn_exp2f(x)

// async global->LDS, 16B per lane; LDS dest must be waveBase + lane*16
#define GLD16(gptr, lptr)                                                      \
    __builtin_amdgcn_global_load_lds(                                          \
        (const __attribute__((address_space(1))) void*)(gptr),                 \
        (__attribute__((address_space(3))) void*)(lptr), 16, 0, 0)

typedef float f32x4 __attribute__((ext_vector_type(4)));
typedef _Float16 half8 __attribute__((ext_vector_type(8)));
typedef _Float16 half4 __attribute__((ext_vector_type(4)));
typedef _Float16 half2v __attribute__((ext_vector_type(2)));

static __device__ __forceinline__ f32x4 mfma_16x16x32(half8 a, half8 b, f32x4 c) {
    return __builtin_amdgcn_mfma_f32_16x16x32_f16(a, b, c, 0, 0, 0);
}
// NOTE: legacy K=16 shape is spelled WITHOUT the underscore: ...16x16x16f16
static __device__ __forceinline__ f32x4 mfma_16x16x16(half4 a, half4 b, f32x4 c) {
    return __builtin_amdgcn_mfma_f32_16x16x16f16(a, b, c, 0, 0, 0);
}
static __device__ __forceinline__ half4 lo4(half8 v) {
    return __builtin_shufflevector(v, v, 0, 1, 2, 3);
}
static __device__ __forceinline__ half4 hi4(half8 v) {
    return __builtin_shufflevector(v, v, 4, 5, 6, 7);
}

// ---------------------------------------------------------------------------
// One fused cast kernel for the three fp32->f16 conversions.
__global__ __launch_bounds__(256)
void cast_all(const float* __restrict__ hs, const float* __restrict__ wq,
              const float* __restrict__ wp, _Float16* __restrict__ dhs,
              _Float16* __restrict__ dwq, _Float16* __restrict__ dwp) {
    const int n1 = SEQLEN * DIMM / 4, n2 = QKV_N * DIMM / 4, n3 = DIMM * DIMM / 4;
    int i = blockIdx.x * 256 + threadIdx.x;
    const float4* src; half4* dst; int j;
    if (i < n1)           { src = (const float4*)hs; dst = (half4*)dhs; j = i; }
    else if (i < n1 + n2) { src = (const float4*)wq; dst = (half4*)dwq; j = i - n1; }
    else if (i < n1 + n2 + n3) { src = (const float4*)wp; dst = (half4*)dwp; j = i - n1 - n2; }
    else return;
    const float4 v = src[j];
    half4 h;
    h.x = (_Float16)v.x; h.y = (_Float16)v.y;
    h.z = (_Float16)v.z; h.w = (_Float16)v.w;
    dst[j] = h;
}

// ---------------------------------------------------------------------------
// 128x128 block tile, 8 waves 4x2 (each 32x64, 2x4 mfma tiles), BK=64 as two
// BK=32 panels. Per K-iter per thread: 4 GLD16 (one per matrix per panel);
// per wave: 16 MFMA + 12 ds_read_b128. 32 KB LDS -> 2 blocks/CU.
template<bool OUT_F16>
__global__ __launch_bounds__(512, 4)
void gemm_bt128(const _Float16* __restrict__ A, const _Float16* __restrict__ B,
                const float* __restrict__ bias, void* __restrict__ Cout,
                int M, int N, int K) {
    __shared__ __align__(16) _Float16 As[2][128 * 32];   // 16 KB
    __shared__ __align__(16) _Float16 Bs[2][128 * 32];   // 16 KB
    const int tid  = threadIdx.x;
    const int lane = tid & 63;
    const int wave = tid >> 6;
    const int l15  = lane & 15;
    const int quad = lane >> 4;
    const int wm   = wave & 3;           // 4 row-waves of 32
    const int wn   = wave >> 2;          // 2 col-waves of 64
    const long bm = blockIdx.x, bn = blockIdx.y;

    const _Float16* Ag = A + bm * 128 * (long)K;
    const _Float16* Bg = B + bn * 128 * (long)K;

    const int srow = lane >> 2;            // 0..15 within wave's 16-row strip
    const int scol = (lane & 3) * 8;       // halves
    f32x4 acc[2][4] = {};

    for (int k0 = 0; k0 < K; k0 += 64) {
        __syncthreads();
#pragma unroll
        for (int p = 0; p < 2; p++) {
            const int kp = k0 + p * 32;
            const long r = 16 * wave + srow;        // 0..127
            GLD16(Ag + r * K + kp + scol, &As[p][512 * wave + lane * 8]);
            GLD16(Bg + r * K + kp + scol, &Bs[p][512 * wave + lane * 8]);
        }
        __syncthreads();
#pragma unroll
        for (int p = 0; p < 2; p++) {
            half8 af[2], bf[4];
#pragma unroll
            for (int t = 0; t < 2; t++)
                af[t] = *(const half8*)&As[p][(wm * 32 + t * 16 + l15) * 32 + quad * 8];
#pragma unroll
            for (int t = 0; t < 4; t++)
                bf[t] = *(const half8*)&Bs[p][(wn * 64 + t * 16 + l15) * 32 + quad * 8];
#pragma unroll
            for (int mt = 0; mt < 2; mt++)
#pragma unroll
                for (int nt = 0; nt < 4; nt++)
                    acc[mt][nt] = mfma_16x16x32(af[mt], bf[nt], acc[mt][nt]);
        }
    }

    float bv[4];
#pragma unroll
    for (int nt = 0; nt < 4; nt++)
        bv[nt] = bias[bn * 128 + wn * 64 + nt * 16 + l15];

#pragma unroll
    for (int mt = 0; mt < 2; mt++) {
#pragma unroll
        for (int r = 0; r < 4; r++) {
            const long row = bm * 128 + wm * 32 + mt * 16 + quad * 4 + r;
#pragma unroll
            for (int nt = 0; nt < 4; nt++) {
                const long col = bn * 128 + wn * 64 + nt * 16 + l15;
                const float v = acc[mt][nt][r] + bv[nt];
                if (OUT_F16) ((_Float16*)Cout)[row * (long)N + col] = (_Float16)v;
                else         ((float*)Cout)[row * (long)N + col] = v;
            }
        }
    }
}

// ---------------------------------------------------------------------------
// 64x128 tile, 4 waves (proj GEMM: keeps grid >=256 blocks).
template<bool OUT_F16>
__global__ __launch_bounds__(256, 2)
void gemm_bt64(const _Float16* __restrict__ A, const _Float16* __restrict__ B,
               const float* __restrict__ bias, void* __restrict__ Cout,
               int M, int N, int K) {
    __shared__ __align__(16) _Float16 As[2][64 * 32];    // 8 KB
    __shared__ __align__(16) _Float16 Bs[2][128 * 32];   // 16 KB
    const int tid  = threadIdx.x;
    const int lane = tid & 63;
    const int wave = tid >> 6;
    const int l15  = lane & 15;
    const int quad = lane >> 4;
    const int wm   = wave & 1;
    const int wn   = wave >> 1;
    const long bm = blockIdx.x, bn = blockIdx.y;

    const _Float16* Ag = A + bm * 64 * (long)K;
    const _Float16* Bg = B + bn * 128 * (long)K;

    const int srow = lane >> 2;            // 0..15 within chunk
    const int scol = (lane & 3) * 8;       // halves
    f32x4 acc[2][4] = {};

    for (int k0 = 0; k0 < K; k0 += 64) {
        __syncthreads();
#pragma unroll
        for (int p = 0; p < 2; p++) {
            const int kp = k0 + p * 32;
            const long arow = 16 * wave + srow;
            GLD16(Ag + arow * K + kp + scol, &As[p][512 * wave + lane * 8]);
#pragma unroll
            for (int cc = 0; cc < 2; cc++) {
                const int c = wave + cc * 4;
                const long brow = 16 * c + srow;
                GLD16(Bg + brow * K + kp + scol, &Bs[p][512 * c + lane * 8]);
            }
        }
        __syncthreads();
#pragma unroll
        for (int p = 0; p < 2; p++) {
            half8 af[2], bf[4];
#pragma unroll
            for (int t = 0; t < 2; t++)
                af[t] = *(const half8*)&As[p][(wm * 32 + t * 16 + l15) * 32 + quad * 8];
#pragma unroll
            for (int t = 0; t < 4; t++)
                bf[t] = *(const half8*)&Bs[p][(wn * 64 + t * 16 + l15) * 32 + quad * 8];
#pragma unroll
            for (int mt = 0; mt < 2; mt++)
#pragma unroll
                for (int nt = 0; nt < 4; nt++)
                    acc[mt][nt] = mfma_16x16x32(af[mt], bf[nt], acc[mt][nt]);
        }
    }

    float bv[4];
#pragma unroll
    for (int nt = 0; nt < 4; nt++)
        bv[nt] = bias[bn * 128 + wn * 64 + nt * 16 + l15];

#pragma unroll
    for (int mt = 0; mt < 2; mt++) {
#pragma unroll
        for (int r = 0; r < 4; r++) {
            const long row = bm * 64 + wm * 32 + mt * 16 + quad * 4 + r;
#pragma unroll
            for (int nt = 0; nt < 4; nt++) {
                const long col = bn * 128 + wn * 64 + nt * 16 + l15;
                const float v = acc[mt][nt][r] + bv[nt];
                if (OUT_F16) ((_Float16*)Cout)[row * (long)N + col] = (_Float16)v;
                else         ((float*)Cout)[row * (long)N + col] = v;
            }
        }
    }
}

// ---------------------------------------------------------------------------
// Fused: RoPE on q,k -> Qh/Kh [h][s][80] dense (Q pre-scaled by SCALE*log2e)
// + V transposed via LDS -> Vt[h][d][s]. Block = (64 seqs, 1 head).
__global__ __launch_bounds__(256)
void rope_repack_t(const _Float16* __restrict__ qkv,
                   const float* __restrict__ cosb,
                   const float* __restrict__ sinb,
                   _Float16* __restrict__ Qh,
                   _Float16* __restrict__ Kh,
                   _Float16* __restrict__ Vt) {
    const int s0 = blockIdx.x * 64;
    const int h  = blockIdx.y;
    __shared__ __align__(16) _Float16 Ts[64 * 88];
    const int tid = threadIdx.x;

    // stage V rows into LDS (transposed write later)
    for (int i = tid; i < 640; i += 256) {          // 64 rows x 10 chunks
        const int r = i / 10, c = (i - r * 10) * 8;
        *(half8*)&Ts[r * 88 + c] =
            *(const half8*)&qkv[(long)(s0 + r) * QKV_N + 2 * DIMM + h * HD + c];
    }

    // q,k rope: 64 rows x 5 chunks of 8 (d in [0,40))
    for (int i = tid; i < 320; i += 256) {
        const int r = i / 5, d = (i - r * 5) * 8;
        const _Float16* row = qkv + (long)(s0 + r) * QKV_N + h * HD;
        const half8 q0 = *(const half8*)&row[d];
        const half8 q1 = *(const half8*)&row[d + 40];
        const half8 k0 = *(const half8*)&row[DIMM + d];
        const half8 k1 = *(const half8*)&row[DIMM + d + 40];
        const float4 cA = *(const float4*)&cosb[(s0 + r) * HD + d];
        const float4 cB = *(const float4*)&cosb[(s0 + r) * HD + d + 4];
        const float4 sA = *(const float4*)&sinb[(s0 + r) * HD + d];
        const float4 sB = *(const float4*)&sinb[(s0 + r) * HD + d + 4];
        half8 qo0, qo1, ko0, ko1;
#pragma unroll
        for (int j = 0; j < 8; j++) {
            const float cj = (j < 4) ? cA[j] : cB[j - 4];
            const float sj = (j < 4) ? sA[j] : sB[j - 4];
            qo0[j] = (_Float16)(((float)q0[j] * cj - (float)q1[j] * sj) * QSCALE_LOG2E);
            qo1[j] = (_Float16)(((float)q1[j] * cj + (float)q0[j] * sj) * QSCALE_LOG2E);
            ko0[j] = (_Float16)((float)k0[j] * cj - (float)k1[j] * sj);
            ko1[j] = (_Float16)((float)k1[j] * cj + (float)k0[j] * sj);
        }
        const long o = ((long)h * SEQLEN + s0 + r) * HD;
        *(half8*)&Qh[o + d]      = qo0;
        *(half8*)&Qh[o + d + 40] = qo1;
        *(half8*)&Kh[o + d]      = ko0;
        *(half8*)&Kh[o + d + 40] = ko1;
    }
    __syncthreads();
    // transposed V out: 80 d-rows x 8 s-chunks
    for (int i = tid; i < 640; i += 256) {
        const int d = i >> 3, sc = (i & 7) * 8;
        half8 v;
#pragma unroll
        for (int j = 0; j < 8; j++) v[j] = Ts[(sc + j) * 88 + d];
        *(half8*)&Vt[((long)h * HD + d) * SEQLEN + s0 + sc] = v;
    }
}

// ---------------------------------------------------------------------------
// Flash attention v4: 8 waves x 32 q-rows (TWO 16-row Q fragments per wave)
// = 256 q-rows/block; 64-key tiles; KV-split x4. Every K/V LDS read feeds
// BOTH fragments' MFMAs (kf/va are fragment-independent) — LDS read traffic
// per unit work halves vs v3 (it was ~45% of kernel time). Same proven
// 2-barrier loop, hoisted staging offsets, loads issued before barrier-1.
// LDS 26 KB; VGPR target <=128 (512,4) -> 2 blocks/CU.
__global__ __launch_bounds__(512, 4)
void attn_kernel(const _Float16* __restrict__ Qh, const _Float16* __restrict__ Kh,
                 const _Float16* __restrict__ Vt,
                 _Float16* __restrict__ Ohat0, _Float16* __restrict__ Ohat1,
                 float* __restrict__ Lpart) {
    const int s0 = blockIdx.x * 256;
    const int h  = blockIdx.y;
    const int z  = blockIdx.z;
    __shared__ __align__(16) _Float16 Ks[64 * KSTRIDE];        // 11.0 KB
    __shared__ __align__(16) _Float16 VF[5 * 64 * VFSTRIDE];   // 15.0 KB

    const int tid  = threadIdx.x;
    const int lane = tid & 63;
    const int wave = tid >> 6;
    const int l15  = lane & 15;
    const int quad = lane >> 4;

    const int zBeg = z * KVSPAN, zEnd = zBeg + KVSPAN;

    // Q fragments (persistent): two 16-row fragments, dense 80 each
    const _Float16* Qg0 = Qh + ((long)h * SEQLEN + s0 + wave * 32 + l15) * HD;
    const _Float16* Qg1 = Qg0 + 16 * (long)HD;
    const half8 qA0 = *(const half8*)&Qg0[quad * 8];
    const half8 qA1 = *(const half8*)&Qg0[32 + quad * 8];
    const half4 qA2 = *(const half4*)&Qg0[64 + quad * 4];
    const half8 qB0 = *(const half8*)&Qg1[quad * 8];
    const half8 qB1 = *(const half8*)&Qg1[32 + quad * 8];
    const half4 qB2 = *(const half4*)&Qg1[64 + quad * 4];

    // ---- hoisted staging assignment (all div/mod at init only) ----
    // 640 K chunks (64 rows x 10) + 640 V chunks (80 d-rows x 8) = 1280:
    //  slot A (all 512):   K chunks [0,512)
    //  slot B (tid<128):   K chunks [512,640)   | (tid>=128): V chunks [0,384)
    //  slot C (tid<256):   V chunks [384,640)
    // Branch boundaries are wave-aligned (128, 256).
    int offA, dsA, offB, dsB0, dsB1 = 0, offC = 0, dsC0 = 0, dsC1 = 0;
    {
        const int rA = tid / 10, cA = (tid - rA * 10) * 8;
        offA = rA * HD + cA;
        dsA  = rA * KSTRIDE + cA;
        if (tid < 128) {
            const int cB = tid + 512;
            const int rB = cB / 10, ccB = (cB - rB * 10) * 8;
            offB = rB * HD + ccB;
            dsB0 = rB * KSTRIDE + ccB;
        } else {
            const int v = tid - 128, d = v >> 3, c8 = (v & 7) * 8;
            offB = d * SEQLEN + c8;
            const int nt = d >> 4, ld = d & 15, ct = c8 >> 4, qb = (c8 & 15) >> 2;
            dsB0 = (nt * 64 + qb * 16 + ld) * VFSTRIDE + ct * 4;
            dsB1 = (nt * 64 + (qb + 1) * 16 + ld) * VFSTRIDE + ct * 4;
        }
        if (tid < 256) {
            const int v = tid + 384, d = v >> 3, c8 = (v & 7) * 8;
            offC = d * SEQLEN + c8;
            const int nt = d >> 4, ld = d & 15, ct = c8 >> 4, qb = (c8 & 15) >> 2;
            dsC0 = (nt * 64 + qb * 16 + ld) * VFSTRIDE + ct * 4;
            dsC1 = (nt * 64 + (qb + 1) * 16 + ld) * VFSTRIDE + ct * 4;
        }
    }
    const _Float16* KzBase = Kh + ((long)h * SEQLEN + zBeg) * HD;
    const _Float16* VzBase = Vt + (long)h * HD * SEQLEN + zBeg;

    f32x4 oaccA[5] = {}, oaccB[5] = {};
    float laA0 = 0.f, laA1 = 0.f, laB0 = 0.f, laB1 = 0.f;
    const half2v ones2 = {(_Float16)1.f, (_Float16)1.f};

    for (int t0 = zBeg; t0 < zEnd; t0 += 64) {
        // issue this tile's loads BEFORE the barrier: they fly while other
        // waves finish the previous tile's compute.
        const _Float16* KzT = KzBase + (long)(t0 - zBeg) * HD;
        const _Float16* VzT = VzBase + (t0 - zBeg);
        const half8 a = *(const half8*)(KzT + offA);
        half8 b;
        if (tid < 128) b = *(const half8*)(KzT + offB);
        else           b = *(const half8*)(VzT + offB);
        half8 cv = {};
        if (tid < 256) cv = *(const half8*)(VzT + offC);

        __syncthreads();                       // all waves done reading LDS
        *(half8*)&Ks[dsA] = a;
        if (tid < 128) { *(half8*)&Ks[dsB0] = b; }
        else {
            *(half4*)&VF[dsB0] = lo4(b);
            *(half4*)&VF[dsB1] = hi4(b);
        }
        if (tid < 256) {
            *(half4*)&VF[dsC0] = lo4(cv);
            *(half4*)&VF[dsC1] = hi4(cv);
        }
        __syncthreads();                       // LDS ready

        // S^T: 4 col-tiles of 16 keys; each kf read feeds BOTH fragments.
        f32x4 saA[4] = {}, saB[4] = {};
        __builtin_amdgcn_s_setprio(1);
#pragma unroll
        for (int ct = 0; ct < 4; ct++) {
            const int kb = (ct * 16 + l15) * KSTRIDE;
            const half8 kf0 = *(const half8*)&Ks[kb + quad * 8];
            const half8 kf1 = *(const half8*)&Ks[kb + 32 + quad * 8];
            const half4 kf2 = *(const half4*)&Ks[kb + 64 + quad * 4];
            saA[ct] = mfma_16x16x32(kf0, qA0, saA[ct]);
            saB[ct] = mfma_16x16x32(kf0, qB0, saB[ct]);
            saA[ct] = mfma_16x16x32(kf1, qA1, saA[ct]);
            saB[ct] = mfma_16x16x32(kf1, qB1, saB[ct]);
            saA[ct] = mfma_16x16x16(kf2, qA2, saA[ct]);
            saB[ct] = mfma_16x16x16(kf2, qB2, saB[ct]);
        }
        __builtin_amdgcn_s_setprio(0);

        // P^T = exp2(S^T): cvt_pkrtz feeds the PV B-operand and v_dot2 l-accum
        half4 pbA[4], pbB[4];
#pragma unroll
        for (int ct = 0; ct < 4; ct++) {
            {
                const float e0 = EXP2F(saA[ct][0]);
                const float e1 = EXP2F(saA[ct][1]);
                const float e2 = EXP2F(saA[ct][2]);
                const float e3 = EXP2F(saA[ct][3]);
                const half2v p01 = __builtin_bit_cast(half2v, __builtin_amdgcn_cvt_pkrtz(e0, e1));
                const half2v p23 = __builtin_bit_cast(half2v, __builtin_amdgcn_cvt_pkrtz(e2, e3));
                laA0 = __builtin_amdgcn_fdot2(p01, ones2, laA0, false);
                laA1 = __builtin_amdgcn_fdot2(p23, ones2, laA1, false);
                pbA[ct] = __builtin_shufflevector(p01, p23, 0, 1, 2, 3);
            }
            {
                const float e0 = EXP2F(saB[ct][0]);
                const float e1 = EXP2F(saB[ct][1]);
                const float e2 = EXP2F(saB[ct][2]);
                const float e3 = EXP2F(saB[ct][3]);
                const half2v p01 = __builtin_bit_cast(half2v, __builtin_amdgcn_cvt_pkrtz(e0, e1));
                const half2v p23 = __builtin_bit_cast(half2v, __builtin_amdgcn_cvt_pkrtz(e2, e3));
                laB0 = __builtin_amdgcn_fdot2(p01, ones2, laB0, false);
                laB1 = __builtin_amdgcn_fdot2(p23, ones2, laB1, false);
                pbB[ct] = __builtin_shufflevector(p01, p23, 0, 1, 2, 3);
            }
        }

        // O^T += V^T * P^T : each va/vb read feeds BOTH fragments (8 MFMA / 2 reads)
        __builtin_amdgcn_s_setprio(1);
#pragma unroll
        for (int nt = 0; nt < 5; nt++) {
            const half8 va = *(const half8*)&VF[(nt * 64 + lane) * VFSTRIDE];
            const half8 vb = *(const half8*)&VF[(nt * 64 + lane) * VFSTRIDE + 8];
            oaccA[nt] = mfma_16x16x16(lo4(va), pbA[0], oaccA[nt]);
            oaccB[nt] = mfma_16x16x16(lo4(va), pbB[0], oaccB[nt]);
            oaccA[nt] = mfma_16x16x16(hi4(va), pbA[1], oaccA[nt]);
            oaccB[nt] = mfma_16x16x16(hi4(va), pbB[1], oaccB[nt]);
            oaccA[nt] = mfma_16x16x16(lo4(vb), pbA[2], oaccA[nt]);
            oaccB[nt] = mfma_16x16x16(lo4(vb), pbB[2], oaccB[nt]);
            oaccA[nt] = mfma_16x16x16(hi4(vb), pbA[3], oaccA[nt]);
            oaccB[nt] = mfma_16x16x16(hi4(vb), pbB[3], oaccB[nt]);
        }
        __builtin_amdgcn_s_setprio(0);
    }

    // l: sum the 4 quads holding each query's key-chunks
    float lA = laA0 + laA1, lB = laB0 + laB1;
    lA += __shfl_xor(lA, 16); lA += __shfl_xor(lA, 32);
    lB += __shfl_xor(lB, 16); lB += __shfl_xor(lB, 32);
    const float invA = 1.0f / lA, invB = 1.0f / lB;

    // partials: z 0,1 -> Ohat0 region, z 2,3 -> Ohat1 region
    _Float16* Oz = (z < 2) ? Ohat0 : Ohat1;
    const long obase = ((long)(z & 1) * NHEADS + h) * SEQLEN;
    const long lbase = ((long)z * NHEADS + h) * SEQLEN;
    const long rowA = s0 + wave * 32 + l15;
    const long rowB = rowA + 16;
#pragma unroll
    for (int nt = 0; nt < 5; nt++) {
        half4 oA, oB;
#pragma unroll
        for (int r = 0; r < 4; r++) {
            oA[r] = (_Float16)(oaccA[nt][r] * invA);
            oB[r] = (_Float16)(oaccB[nt][r] * invB);
        }
        *(half4*)&Oz[(obase + rowA) * HD + nt * 16 + quad * 4] = oA;
        *(half4*)&Oz[(obase + rowB) * HD + nt * 16 + quad * 4] = oB;
    }
    if (quad == 0) {
        Lpart[lbase + rowA] = lA;
        Lpart[lbase + rowB] = lB;
    }
}

// ---------------------------------------------------------------------------
// out = sum_z Ohat_z * l_z / sum_z l_z  -> attnb f16 [s][h*80+d]
__global__ __launch_bounds__(256)
void attn_combine(const _Float16* __restrict__ Ohat0,
                  const _Float16* __restrict__ Ohat1,
                  const float* __restrict__ Lp,
                  _Float16* __restrict__ attnb) {
    const int i = blockIdx.x * 256 + threadIdx.x;
    if (i >= SEQLEN * DIMM / 4) return;
    const int flat = i * 4;
    const int s = flat / DIMM;
    const int rem = flat - s * DIMM;
    const int h = rem / HD;
    const int d = rem - h * HD;
    float l[NSPLIT], lsum = 0.f;
#pragma unroll
    for (int zi = 0; zi < NSPLIT; zi++) {
        l[zi] = Lp[((long)zi * NHEADS + h) * SEQLEN + s];
        lsum += l[zi];
    }
    const float invl = 1.0f / lsum;
    float acc[4] = {0.f, 0.f, 0.f, 0.f};
#pragma unroll
    for (int zi = 0; zi < NSPLIT; zi++) {
        const _Float16* Oz = (zi < 2) ? Ohat0 : Ohat1;
        const long obase = ((long)(zi & 1) * NHEADS + h) * SEQLEN;
        const half4 o = *(const half4*)&Oz[(obase + s) * HD + d];
        const float w = l[zi] * invl;
#pragma unroll
        for (int j = 0; j < 4; j++) acc[j] += (float)o[j] * w;
    }
    half4 o;
#pragma unroll
    for (int j = 0; j < 4; j++) o[j] = (_Float16)acc[j];
    *(half4*)&attnb[(long)s * DIMM + rem] = o;
}

// ---------------------------------------------------------------------------
extern "C" void kernel_launch(void* const* d_in, const int* in_sizes, int n_in,
                              void* d_out, int out_size, void* d_ws, size_t ws_size,
                              hipStream_t stream) {
    const float* hs     = (const float*)d_in[0];
    // d_in[1] = cu_seqlens [0, 2048] — reference does no masking; unused.
    const float* cosb   = (const float*)d_in[2];
    const float* sinb   = (const float*)d_in[3];
    const float* w_qkv  = (const float*)d_in[4];
    const float* b_qkv  = (const float*)d_in[5];
    const float* w_proj = (const float*)d_in[6];
    const float* b_proj = (const float*)d_in[7];
    float* out = (float*)d_out;

    _Float16* hsb    = (_Float16*)d_ws;                       // 2048*1280
    _Float16* wqkvb  = hsb    + (long)SEQLEN * DIMM;          // 3840*1280
    _Float16* wprojb = wqkvb  + (long)QKV_N * DIMM;           // 1280*1280
    _Float16* qkv    = wprojb + (long)DIMM * DIMM;            // 2048*3840
    _Float16* Qh     = qkv    + (long)SEQLEN * QKV_N;         // 16*2048*80
    _Float16* Kh     = Qh     + (long)NHEADS * SEQLEN * HD;
    _Float16* Vtb    = Kh     + (long)NHEADS * SEQLEN * HD;   // 16*80*2048
    _Float16* attnb  = Vtb    + (long)NHEADS * HD * SEQLEN;   // 2048*1280

    // attention partials alias DEAD regions during attention:
    //   Ohat0 (z=0,1): hsb+wqkvb region (15.07 MB) — dead after QKV GEMM.
    //   Ohat1 (z=2,3): qkv region (15.73 MB) — dead after rope_repack_t.
    _Float16* Ohat0  = (_Float16*)d_ws;
    float*    LpartB = (float*)(Ohat0 + (long)2 * NHEADS * SEQLEN * HD);
    _Float16* Ohat1  = qkv;

    {
        const int ntot = (SEQLEN * DIMM + QKV_N * DIMM + DIMM * DIMM) / 4;
        cast_all<<<(ntot + 255) / 256, 256, 0, stream>>>(
            hs, w_qkv, w_proj, hsb, wqkvb, wprojb);
    }

    gemm_bt128<true><<<dim3(SEQLEN / 128, QKV_N / 128), 512, 0, stream>>>(
        hsb, wqkvb, b_qkv, qkv, SEQLEN, QKV_N, DIMM);

    rope_repack_t<<<dim3(SEQLEN / 64, NHEADS), 256, 0, stream>>>(
        qkv, cosb, sinb, Qh, Kh, Vtb);

    attn_kernel<<<dim3(SEQLEN / 256, NHEADS, NSPLIT), 512, 0, stream>>>(
        Qh, Kh, Vtb, Ohat0, Ohat1, LpartB);

    attn_combine<<<(SEQLEN * DIMM / 4 + 255) / 256, 256, 0, stream>>>(
        Ohat0, Ohat1, LpartB, attnb);

    gemm_bt64<false><<<dim3(SEQLEN / 64, DIMM / 128), 256, 0, stream>>>(
        attnb, wprojb, b_proj, out, SEQLEN, DIMM, DIMM);
}